// Round 1
// baseline (433.836 us; speedup 1.0000x reference)
//
#include <hip/hip_runtime.h>
#include <math.h>

#define Bq 4
#define Cq 64
#define Hq 160
#define Wq 160
#define HWq (Hq*Wq)      // 25600
#define K2q 9
#define OUTq 64

// ---------------------------------------------------------------------------
// K0a: transpose x [B][C][H][W] -> xt [B][H][W][C]  (NHWC, c contiguous)
// ---------------------------------------------------------------------------
__global__ void __launch_bounds__(256) k_transpose_x(const float* __restrict__ x,
                                                     float* __restrict__ xt) {
    __shared__ float tile[64][65];   // +1 pad: conflict-free transposed reads
    int b    = blockIdx.y;
    int hw0  = blockIdx.x * 64;
    int lane = threadIdx.x & 63;
    int grp  = threadIdx.x >> 6;     // 0..3
#pragma unroll
    for (int i = 0; i < 16; ++i) {
        int c = grp * 16 + i;
        tile[c][lane] = x[(b*Cq + c)*HWq + hw0 + lane];   // coalesced load
    }
    __syncthreads();
#pragma unroll
    for (int i = 0; i < 16; ++i) {
        int hw = grp * 16 + i;
        xt[(b*HWq + hw0 + hw)*64 + lane] = tile[lane][hw]; // coalesced store
    }
}

// ---------------------------------------------------------------------------
// K0b: weight re-layouts.
//   wt[c][k][o]  = dcn_w[o][c][k]          (36864 elems)
//   cw[c][k][co] = {offset_w|mask_w}[co][c][k]  (co 0..17 offset, 18..26 mask)
// ---------------------------------------------------------------------------
__global__ void __launch_bounds__(256) k_relayout_w(const float* __restrict__ dcn_w,
                                                    const float* __restrict__ off_w,
                                                    const float* __restrict__ msk_w,
                                                    float* __restrict__ wt,
                                                    float* __restrict__ cw) {
    int id = blockIdx.x * 256 + threadIdx.x;
    if (id < Cq*K2q*OUTq) {
        int o = id & 63;
        int k = (id >> 6) % 9;
        int c = id / (64*9);
        wt[id] = dcn_w[(o*Cq + c)*9 + k];
    }
    int id2 = id - Cq*K2q*OUTq;
    if (id2 >= 0 && id2 < Cq*K2q*27) {
        int co = id2 % 27;
        int k  = (id2 / 27) % 9;
        int c  = id2 / (27*9);
        cw[id2] = (co < 18) ? off_w[(co*Cq + c)*9 + k]
                            : msk_w[((co-18)*Cq + c)*9 + k];
    }
}

// ---------------------------------------------------------------------------
// K1: offset+mask 3x3 conv (zero pad), thread per pixel, 27 accumulators.
// Writes om[b][i][j][27]: ch 0..17 raw offsets, 18..26 sigmoid(mask).
// ---------------------------------------------------------------------------
__global__ void __launch_bounds__(256) k_offmask(const float* __restrict__ x,
                                                 const float* __restrict__ off_b,
                                                 const float* __restrict__ msk_b,
                                                 const float* __restrict__ cw,
                                                 float* __restrict__ om) {
    int g = blockIdx.x * 256 + threadIdx.x;   // pixel id < 102400
    int b   = g / HWq;
    int rem = g % HWq;
    int i   = rem / Wq;
    int j   = rem % Wq;

    float acc[27];
#pragma unroll
    for (int co = 0; co < 18; ++co) acc[co] = off_b[co];
#pragma unroll
    for (int co = 0; co < 9; ++co)  acc[18+co] = msk_b[co];

    const float* xb = x + b*Cq*HWq;
    for (int dy = 0; dy < 3; ++dy) {
        int y = i + dy - 1;
        if (y < 0 || y >= Hq) continue;
        for (int dx = 0; dx < 3; ++dx) {
            int xx = j + dx - 1;
            if (xx < 0 || xx >= Wq) continue;
            int tap = dy*3 + dx;
            const float* xp  = xb + y*Wq + xx;
            const float* cwt = cw + tap*27;
            for (int c = 0; c < Cq; ++c) {
                float xv = xp[c*HWq];                 // coalesced across lanes (j)
                const float* wr = cwt + c*9*27;       // uniform -> s_load
#pragma unroll
                for (int co = 0; co < 27; ++co)
                    acc[co] = fmaf(xv, wr[co], acc[co]);
            }
        }
    }
    float* op = om + g*27;
#pragma unroll
    for (int co = 0; co < 18; ++co) op[co] = acc[co];
#pragma unroll
    for (int co = 0; co < 9; ++co)
        op[18+co] = 1.0f / (1.0f + __expf(-acc[18+co]));
}

// ---------------------------------------------------------------------------
// K2: deformable sampling + per-pixel matmul.
// Block = 16 pixels (one row segment), 256 threads (4 waves).
// ---------------------------------------------------------------------------
__global__ void __launch_bounds__(256) k_deform(const float* __restrict__ xt,
                                                const float* __restrict__ om,
                                                const float* __restrict__ wt,
                                                float* __restrict__ out) {
    int blk = blockIdx.x;                 // 6400 = 4 * 160 * 10
    int jt  = blk % (Wq/16);
    int i   = (blk / (Wq/16)) % Hq;
    int b   = blk / ((Wq/16) * Hq);
    int j0  = jt * 16;
    int tid  = threadIdx.x;
    int lane = tid & 63;
    int grp  = tid >> 6;                  // 0..3

    __shared__ __align__(16) float s_s[16*64*12];  // [p][c][12] (k padded) 48KB
    __shared__ int   s_y0[144], s_x0[144];
    __shared__ float s_wy[144], s_wx[144], s_m[144];

    // -------- Phase A: tap coordinates / weights (16 pixels x 9 taps) -----
    if (tid < 144) {
        int p = tid & 15;
        int k = tid >> 4;
        const float* op = om + (((b*Hq + i)*Wq) + j0 + p)*27;
        float oy = op[2*k], ox = op[2*k+1];
        s_m[tid] = op[18+k];
        float py = oy + (float)(i - 1 + k/3);
        float px = ox + (float)(j0 + p - 1 + k%3);
        float fy = floorf(py), fx = floorf(px);
        s_y0[tid] = (int)fy;  s_x0[tid] = (int)fx;
        s_wy[tid] = py - fy;  s_wx[tid] = px - fx;
    }
    __syncthreads();

    // -------- Phase B: bilinear sampling. wave = (p,k), c = lane ----------
    const float* xtb = xt + (size_t)b*HWq*64;
    for (int iter = 0; iter < 36; ++iter) {
        int pk = iter*4 + grp;            // 0..143, each exactly once
        int p  = pk & 15;
        int k  = pk >> 4;
        int y0 = s_y0[pk], x0 = s_x0[pk];
        float wy1 = s_wy[pk], wx1 = s_wx[pk], m = s_m[pk];
        float wy0 = 1.0f - wy1, wx0 = 1.0f - wx1;
        bool vy0 = (y0   >= 0) & (y0   < Hq);
        bool vy1 = (y0+1 >= 0) & (y0+1 < Hq);
        bool vx0 = (x0   >= 0) & (x0   < Wq);
        bool vx1 = (x0+1 >= 0) & (x0+1 < Wq);
        int yc0 = min(max(y0,   0), Hq-1), yc1 = min(max(y0+1, 0), Hq-1);
        int xc0 = min(max(x0,   0), Wq-1), xc1 = min(max(x0+1, 0), Wq-1);
        float w00 = (vy0 && vx0) ? wy0*wx0 : 0.0f;
        float w01 = (vy0 && vx1) ? wy0*wx1 : 0.0f;
        float w10 = (vy1 && vx0) ? wy1*wx0 : 0.0f;
        float w11 = (vy1 && vx1) ? wy1*wx1 : 0.0f;
        const float* r0 = xtb + (size_t)(yc0*Wq)*64;
        const float* r1 = xtb + (size_t)(yc1*Wq)*64;
        float v00 = r0[xc0*64 + lane];    // coalesced 256B
        float v01 = r0[xc1*64 + lane];
        float v10 = r1[xc0*64 + lane];
        float v11 = r1[xc1*64 + lane];
        float sv = (w00*v00 + w01*v01 + w10*v10 + w11*v11) * m;
        s_s[(p*64 + lane)*12 + k] = sv;
    }
    __syncthreads();

    // -------- Phase C: matmul. o = lane, 4 pixels per thread --------------
    float acc[4] = {0.f, 0.f, 0.f, 0.f};
    const float* wto = wt + lane;         // wt[(c*9+k)*64 + o]
    for (int c = 0; c < Cq; ++c) {
        float svv[4][9];
#pragma unroll
        for (int pp = 0; pp < 4; ++pp) {
            const float* sp = &s_s[((grp*4 + pp)*64 + c)*12];
            float4 a = *(const float4*)sp;
            float4 d = *(const float4*)(sp + 4);
            svv[pp][0]=a.x; svv[pp][1]=a.y; svv[pp][2]=a.z; svv[pp][3]=a.w;
            svv[pp][4]=d.x; svv[pp][5]=d.y; svv[pp][6]=d.z; svv[pp][7]=d.w;
            svv[pp][8]=sp[8];
        }
#pragma unroll
        for (int k = 0; k < 9; ++k) {
            float wv = wto[(c*9 + k)*64];
#pragma unroll
            for (int pp = 0; pp < 4; ++pp)
                acc[pp] = fmaf(wv, svv[pp][k], acc[pp]);
        }
    }
    __syncthreads();

    // -------- Epilogue: LDS transpose for semi-coalesced NCHW stores ------
    float* trans = s_s;                   // reuse, [o][17] padded
#pragma unroll
    for (int pp = 0; pp < 4; ++pp)
        trans[lane*17 + (grp*4 + pp)] = acc[pp];
    __syncthreads();
    for (int t = tid; t < 1024; t += 256) {
        int o = t >> 4;
        int p = t & 15;
        out[((b*OUTq + o)*Hq + i)*Wq + j0 + p] = trans[o*17 + p];
    }
}

// ---------------------------------------------------------------------------
extern "C" void kernel_launch(void* const* d_in, const int* in_sizes, int n_in,
                              void* d_out, int out_size, void* d_ws, size_t ws_size,
                              hipStream_t stream) {
    const float* x     = (const float*)d_in[0];
    const float* off_w = (const float*)d_in[1];
    const float* off_b = (const float*)d_in[2];
    const float* msk_w = (const float*)d_in[3];
    const float* msk_b = (const float*)d_in[4];
    const float* dcn_w = (const float*)d_in[5];
    float* out = (float*)d_out;

    float* ws = (float*)d_ws;
    float* xt = ws;                       // 6,553,600 floats
    float* om = xt + Bq*HWq*Cq;           // 2,764,800 floats
    float* wt = om + Bq*HWq*27;           // 36,864 floats
    float* cw = wt + Cq*K2q*OUTq;         // 15,552 floats

    hipLaunchKernelGGL(k_transpose_x, dim3(HWq/64, Bq), dim3(256), 0, stream, x, xt);
    hipLaunchKernelGGL(k_relayout_w, dim3((Cq*K2q*OUTq + Cq*K2q*27 + 255)/256),
                       dim3(256), 0, stream, dcn_w, off_w, msk_w, wt, cw);
    hipLaunchKernelGGL(k_offmask, dim3(Bq*HWq/256), dim3(256), 0, stream,
                       x, off_b, msk_b, cw, om);
    hipLaunchKernelGGL(k_deform, dim3(Bq*Hq*(Wq/16)), dim3(256), 0, stream,
                       xt, om, wt, out);
}

// Round 2
// 266.858 us; speedup vs baseline: 1.6257x; 1.6257x over previous
//
#include <hip/hip_runtime.h>
#include <math.h>

#define Bq 4
#define Cq 64
#define Hq 160
#define Wq 160
#define HWq (Hq*Wq)      // 25600
#define K2q 9
#define OUTq 64
#define KKq 576          // Cq*K2q
#define KS  18           // KKq/32
#define SROW 584         // padded kk row length (bf16 units) -> 1168 B, 2-way-free banks

typedef __attribute__((ext_vector_type(8))) short short8;
typedef __attribute__((ext_vector_type(4))) float float4v;

__device__ __forceinline__ float bf2f(unsigned short u) {
    unsigned int v = ((unsigned int)u) << 16;
    return __builtin_bit_cast(float, v);
}
__device__ __forceinline__ unsigned short f2bf(float f) {  // RNE (finite inputs)
    unsigned int u = __builtin_bit_cast(unsigned int, f);
    unsigned int r = u + 0x7fffu + ((u >> 16) & 1u);
    return (unsigned short)(r >> 16);
}

// ---------------------------------------------------------------------------
// K0a: x [B][C][H][W] f32 -> xt [B][H][W][C] bf16 (coalesced both sides)
// ---------------------------------------------------------------------------
__global__ void __launch_bounds__(256) k_transpose_x(const float* __restrict__ x,
                                                     unsigned short* __restrict__ xt) {
    __shared__ float tile[64][65];
    int b = blockIdx.y, hw0 = blockIdx.x * 64;
    int lane = threadIdx.x & 63, grp = threadIdx.x >> 6;
#pragma unroll
    for (int i = 0; i < 16; ++i) {
        int c = grp*16 + i;
        tile[c][lane] = x[(b*Cq + c)*HWq + hw0 + lane];
    }
    __syncthreads();
#pragma unroll
    for (int i = 0; i < 16; ++i) {
        int hw = grp*16 + i;
        xt[((size_t)b*HWq + hw0 + hw)*64 + lane] = f2bf(tile[lane][hw]);
    }
}

// ---------------------------------------------------------------------------
// K0b: pre-swizzled MFMA A-fragments.
//  wtf_hi/lo[((g*18+ks)*64+lane)*8+j] = bf16 of dcn_w[m=g*16+(lane&15)][kk],
//    kk = ks*32 + (lane>>4)*8 + j  (hi + residual lo for precision)
//  cwf: same layout, g=0..1, rows = 18 offset ch + 9 mask ch (+5 zero pad)
// ---------------------------------------------------------------------------
__global__ void k_relayout(const float* __restrict__ dcn_w,
                           const float* __restrict__ off_w,
                           const float* __restrict__ msk_w,
                           unsigned short* __restrict__ wtf_hi,
                           unsigned short* __restrict__ wtf_lo,
                           unsigned short* __restrict__ cwf) {
    int id = blockIdx.x*256 + threadIdx.x;
    if (id < 4*KS*64*8) {
        int j = id & 7, lane = (id>>3) & 63, ks = (id>>9) % KS, g = id/(8*64*KS);
        int kk = ks*32 + (lane>>4)*8 + j;
        int m  = g*16 + (lane&15);
        float w = dcn_w[m*KKq + kk];
        unsigned short hi = f2bf(w);
        wtf_hi[id] = hi;
        wtf_lo[id] = f2bf(w - bf2f(hi));
    }
    int id2 = id - 4*KS*64*8;
    if (id2 >= 0 && id2 < 2*KS*64*8) {
        int j = id2 & 7, lane = (id2>>3) & 63, ks = (id2>>9) % KS, g = id2/(8*64*KS);
        int kk = ks*32 + (lane>>4)*8 + j;
        int co = g*16 + (lane&15);
        float w = 0.f;
        if (co < 18)      w = off_w[co*KKq + kk];
        else if (co < 27) w = msk_w[(co-18)*KKq + kk];
        cwf[id2] = f2bf(w);
    }
}

// ---------------------------------------------------------------------------
// K1: offset+mask conv as MFMA GEMM. Block = 32 pixels (one row seg), 4 waves.
// im2col staging: s_s[p][kk=c*9+k] = x(b, c, i+k/3-1, j+k%3-1) bf16 (0 if OOB)
// ---------------------------------------------------------------------------
__global__ void __launch_bounds__(256) k_offmask(const unsigned short* __restrict__ xt,
                                                 const unsigned short* __restrict__ cwf,
                                                 const float* __restrict__ off_b,
                                                 const float* __restrict__ msk_b,
                                                 float* __restrict__ om) {
    __shared__ __align__(16) unsigned short s_s[32*SROW];   // 37376 B
    int blk = blockIdx.x;                // 3200 = 4*160*5
    int jt = blk % 5, i = (blk/5) % Hq, b = blk/(5*Hq);
    int j0 = jt*32;
    int tid = threadIdx.x, lane = tid & 63, grp = tid >> 6;

    const unsigned short* xtb = xt + (size_t)b*HWq*64;
    for (int iter = 0; iter < 72; ++iter) {
        int t2 = iter*4 + grp;           // 0..287, each (p,k) once
        int p = t2 & 31, k = t2 >> 5;
        int y  = i + (k/3) - 1;
        int xx = j0 + p + (k - (k/3)*3) - 1;
        unsigned short v = 0;
        if (y >= 0 && y < Hq && xx >= 0 && xx < Wq)          // wave-uniform branch
            v = xtb[(y*Wq + xx)*64 + lane];
        s_s[p*SROW + lane*9 + k] = v;
    }
    __syncthreads();

    // MFMA: wave -> tile (gM = rows co, gN = pixel half)
    int gM = grp & 1, gN = grp >> 1;
    int n = lane & 15, quad = lane >> 4;
    float4v acc = {0.f, 0.f, 0.f, 0.f};
    const unsigned short* arow = cwf + ((size_t)(gM*KS)*64 + lane)*8;
    const unsigned short* brow = s_s + (gN*16 + n)*SROW + quad*8;
#pragma unroll
    for (int ks = 0; ks < KS; ++ks) {
        short8 a  = *(const short8*)(arow + ks*512);
        short8 bf = *(const short8*)(brow + ks*32);
        acc = __builtin_amdgcn_mfma_f32_16x16x32_bf16(a, bf, acc, 0, 0, 0);
    }
    int p = gN*16 + n;
    float* op = om + (size_t)((b*Hq + i)*Wq + j0 + p)*27;
#pragma unroll
    for (int r = 0; r < 4; ++r) {
        int co = gM*16 + quad*4 + r;
        if (co < 18) op[co] = acc[r] + off_b[co];
        else if (co < 27) {
            float v = acc[r] + msk_b[co-18];
            op[co] = 1.f/(1.f + __expf(-v));
        }
    }
}

// ---------------------------------------------------------------------------
// K2: bilinear sampling -> B-fragment staging -> MFMA matmul (hi/lo weights)
// Block = 32 pixels (one row seg), 4 waves.
// ---------------------------------------------------------------------------
__global__ void __launch_bounds__(256) k_deform(const unsigned short* __restrict__ xt,
                                                const float* __restrict__ om,
                                                const unsigned short* __restrict__ wtf_hi,
                                                const unsigned short* __restrict__ wtf_lo,
                                                float* __restrict__ out) {
    __shared__ __align__(16) unsigned short s_s[32*SROW];   // 37376 B
    __shared__ int   s_a00[288], s_a01[288], s_a10[288], s_a11[288];
    __shared__ float s_w00[288], s_w01[288], s_w10[288], s_w11[288];
    int blk = blockIdx.x;
    int jt = blk % 5, i = (blk/5) % Hq, b = blk/(5*Hq);
    int j0 = jt*32;
    int tid = threadIdx.x, lane = tid & 63, grp = tid >> 6;

    // Phase A: per (p,tap) coords + premasked corner weights
    for (int t = tid; t < 288; t += 256) {
        int p = t & 31, k = t >> 5;
        const float* op = om + (size_t)((b*Hq + i)*Wq + j0 + p)*27;
        float oy = op[2*k], ox = op[2*k+1], m = op[18+k];
        float py = oy + (float)(i - 1 + k/3);
        float px = ox + (float)(j0 + p - 1 + (k - (k/3)*3));
        float fy = floorf(py), fx = floorf(px);
        int y0 = (int)fy, x0 = (int)fx;
        float wy1 = py - fy, wx1 = px - fx;
        float wy0 = 1.f - wy1, wx0 = 1.f - wx1;
        bool vy0 = (y0 >= 0) & (y0 < Hq),   vy1 = (y0+1 >= 0) & (y0+1 < Hq);
        bool vx0 = (x0 >= 0) & (x0 < Wq),   vx1 = (x0+1 >= 0) & (x0+1 < Wq);
        int yc0 = min(max(y0,   0), Hq-1), yc1 = min(max(y0+1, 0), Hq-1);
        int xc0 = min(max(x0,   0), Wq-1), xc1 = min(max(x0+1, 0), Wq-1);
        s_a00[t] = (yc0*Wq + xc0)*64;  s_a01[t] = (yc0*Wq + xc1)*64;
        s_a10[t] = (yc1*Wq + xc0)*64;  s_a11[t] = (yc1*Wq + xc1)*64;
        s_w00[t] = (vy0 && vx0) ? wy0*wx0*m : 0.f;
        s_w01[t] = (vy0 && vx1) ? wy0*wx1*m : 0.f;
        s_w10[t] = (vy1 && vx0) ? wy1*wx0*m : 0.f;
        s_w11[t] = (vy1 && vx1) ? wy1*wx1*m : 0.f;
    }
    __syncthreads();

    // Phase B: wave = (p,tap), c = lane; coalesced bf16 gathers from NHWC xt
    const unsigned short* xtb = xt + (size_t)b*HWq*64;
    for (int iter = 0; iter < 72; ++iter) {
        int t2 = iter*4 + grp;
        int p = t2 & 31, k = t2 >> 5;
        float v00 = bf2f(xtb[s_a00[t2] + lane]);
        float v01 = bf2f(xtb[s_a01[t2] + lane]);
        float v10 = bf2f(xtb[s_a10[t2] + lane]);
        float v11 = bf2f(xtb[s_a11[t2] + lane]);
        float sv = s_w00[t2]*v00 + s_w01[t2]*v01 + s_w10[t2]*v10 + s_w11[t2]*v11;
        s_s[p*SROW + lane*9 + k] = f2bf(sv);
    }
    __syncthreads();

    // Phase C: wave grp -> o rows [grp*16, +16), both pixel halves
    int n = lane & 15, quad = lane >> 4;
    float4v acc0 = {0.f,0.f,0.f,0.f}, acc1 = {0.f,0.f,0.f,0.f};
    const unsigned short* ah = wtf_hi + ((size_t)(grp*KS)*64 + lane)*8;
    const unsigned short* al = wtf_lo + ((size_t)(grp*KS)*64 + lane)*8;
    const unsigned short* b0 = s_s + n*SROW + quad*8;
    const unsigned short* b1 = s_s + (16 + n)*SROW + quad*8;
#pragma unroll
    for (int ks = 0; ks < KS; ++ks) {
        short8 fa_h = *(const short8*)(ah + ks*512);
        short8 fa_l = *(const short8*)(al + ks*512);
        short8 fb0  = *(const short8*)(b0 + ks*32);
        short8 fb1  = *(const short8*)(b1 + ks*32);
        acc0 = __builtin_amdgcn_mfma_f32_16x16x32_bf16(fa_h, fb0, acc0, 0,0,0);
        acc0 = __builtin_amdgcn_mfma_f32_16x16x32_bf16(fa_l, fb0, acc0, 0,0,0);
        acc1 = __builtin_amdgcn_mfma_f32_16x16x32_bf16(fa_h, fb1, acc1, 0,0,0);
        acc1 = __builtin_amdgcn_mfma_f32_16x16x32_bf16(fa_l, fb1, acc1, 0,0,0);
    }

    // Epilogue: D row = o_local = quad*4+r, col = pixel = n
#pragma unroll
    for (int r = 0; r < 4; ++r) {
        int o = grp*16 + quad*4 + r;
        float* orow = out + (((size_t)b*OUTq + o)*Hq + i)*Wq + j0;
        orow[n]      = acc0[r];
        orow[16 + n] = acc1[r];
    }
}

// ---------------------------------------------------------------------------
extern "C" void kernel_launch(void* const* d_in, const int* in_sizes, int n_in,
                              void* d_out, int out_size, void* d_ws, size_t ws_size,
                              hipStream_t stream) {
    const float* x     = (const float*)d_in[0];
    const float* off_w = (const float*)d_in[1];
    const float* off_b = (const float*)d_in[2];
    const float* msk_w = (const float*)d_in[3];
    const float* msk_b = (const float*)d_in[4];
    const float* dcn_w = (const float*)d_in[5];
    float* out = (float*)d_out;

    char* ws = (char*)d_ws;
    unsigned short* xt     = (unsigned short*)ws;                    // 13,107,200 B
    float*          om     = (float*)(ws + (size_t)Bq*HWq*64*2);     // 11,059,200 B
    unsigned short* wtf_hi = (unsigned short*)((char*)om + (size_t)Bq*HWq*27*4);
    unsigned short* wtf_lo = wtf_hi + 4*KS*64*8;                     // 73,728 B each
    unsigned short* cwf    = wtf_lo + 4*KS*64*8;                     // 36,864 B

    hipLaunchKernelGGL(k_transpose_x, dim3(HWq/64, Bq), dim3(256), 0, stream, x, xt);
    hipLaunchKernelGGL(k_relayout, dim3((4*KS*64*8 + 2*KS*64*8 + 255)/256), dim3(256),
                       0, stream, dcn_w, off_w, msk_w, wtf_hi, wtf_lo, cwf);
    hipLaunchKernelGGL(k_offmask, dim3(Bq*Hq*5), dim3(256), 0, stream,
                       xt, cwf, off_b, msk_b, om);
    hipLaunchKernelGGL(k_deform, dim3(Bq*Hq*5), dim3(256), 0, stream,
                       xt, om, wtf_hi, wtf_lo, out);
}

// Round 3
// 172.911 us; speedup vs baseline: 2.5090x; 1.5433x over previous
//
#include <hip/hip_runtime.h>
#include <math.h>

#define Bq 4
#define Cq 64
#define Hq 160
#define Wq 160
#define HWq (Hq*Wq)      // 25600
#define K2q 9
#define OUTq 64
#define KKq 576          // Cq*K2q
#define KS  18           // KKq/32
#define SROW 584         // padded kk row (bf16 units); b128 reads at LDS floor

typedef __attribute__((ext_vector_type(8))) short short8;
typedef __attribute__((ext_vector_type(4))) float float4v;
typedef unsigned short ushort_t;

__device__ __forceinline__ float bf2f(unsigned short u) {
    unsigned int v = ((unsigned int)u) << 16;
    return __builtin_bit_cast(float, v);
}
__device__ __forceinline__ unsigned short f2bf(float f) {  // RNE (finite inputs)
    unsigned int u = __builtin_bit_cast(unsigned int, f);
    unsigned int r = u + 0x7fffu + ((u >> 16) & 1u);
    return (unsigned short)(r >> 16);
}

// ---------------------------------------------------------------------------
// K0a: x [B][C][H][W] f32 -> xt [B][H][W][C] bf16 (coalesced both sides)
// ---------------------------------------------------------------------------
__global__ void __launch_bounds__(256) k_transpose_x(const float* __restrict__ x,
                                                     ushort_t* __restrict__ xt) {
    __shared__ float tile[64][65];
    int b = blockIdx.y, hw0 = blockIdx.x * 64;
    int lane = threadIdx.x & 63, grp = threadIdx.x >> 6;
#pragma unroll
    for (int i = 0; i < 16; ++i) {
        int c = grp*16 + i;
        tile[c][lane] = x[(b*Cq + c)*HWq + hw0 + lane];
    }
    __syncthreads();
#pragma unroll
    for (int i = 0; i < 16; ++i) {
        int hw = grp*16 + i;
        xt[((size_t)b*HWq + hw0 + hw)*64 + lane] = f2bf(tile[lane][hw]);
    }
}

// ---------------------------------------------------------------------------
// K0b: weight prepack.
//  wtf[((g*18+ks)*64+lane)*8+j]: A-frag of dcn_w, m=g*16+(lane&15),
//        kk = ks*32 + (lane>>4)*8 + j  (kk = c*9+k composite)
//  cwf2[((k*2+g)*2+ks2)*512 + lane*8 + j]: per-tap A-frag of conv weights,
//        co = g*16+(lane&15) (>=27 -> 0), c = ks2*32 + (lane>>4)*8 + j
// ---------------------------------------------------------------------------
__global__ void k_relayout(const float* __restrict__ dcn_w,
                           const float* __restrict__ off_w,
                           const float* __restrict__ msk_w,
                           ushort_t* __restrict__ wtf,
                           ushort_t* __restrict__ cwf2) {
    int id = blockIdx.x*256 + threadIdx.x;
    if (id < 4*KS*512) {
        int j = id & 7, lane = (id>>3) & 63, ks = (id>>9) % KS, g = id/(512*KS);
        int kk = ks*32 + ((lane>>4))*8 + j;
        int m  = g*16 + (lane&15);
        wtf[id] = f2bf(dcn_w[m*KKq + kk]);
    }
    int id2 = id - 4*KS*512;
    if (id2 >= 0 && id2 < 9*2*2*512) {
        int j = id2 & 7, lane = (id2>>3) & 63;
        int ks2 = (id2>>9) & 1, g = (id2>>10) & 1, k = id2 >> 11;
        int co = g*16 + (lane&15);
        int c  = ks2*32 + (lane>>4)*8 + j;
        float w = 0.f;
        if (co < 18)      w = off_w[co*KKq + c*9 + k];
        else if (co < 27) w = msk_w[(co-18)*KKq + c*9 + k];
        cwf2[id2] = f2bf(w);
    }
}

// ---------------------------------------------------------------------------
// K1: offset+mask conv via dense halo tile + per-tap MFMA (9 taps x K=64).
// Block = 32 pixels of one row. Halo: 3 rows x 34 px x 64 ch bf16 in LDS.
// ---------------------------------------------------------------------------
#define HSTRIDE 72   // px stride in ushorts (144 B, 16B-aligned, b128 at floor)
__global__ void __launch_bounds__(256, 6) k_offmask(const ushort_t* __restrict__ xt,
                                                    const ushort_t* __restrict__ cwf2,
                                                    const float* __restrict__ off_b,
                                                    const float* __restrict__ msk_b,
                                                    float* __restrict__ om) {
    __shared__ __align__(16) ushort_t halo[3*34*HSTRIDE];   // 14,688 B
    int blk = blockIdx.x;                 // 3200 = 4*160*5
    int jt = blk % 5, i = (blk/5) % Hq, b = blk/(5*Hq);
    int j0 = jt*32;
    int tid = threadIdx.x, lane = tid & 63, grp = tid >> 6;

    // stage halo: 102 segments x 128 B, vectorized, no dependent chains
    const ushort_t* xtb = xt + (size_t)b*HWq*64;
    for (int t = tid; t < 816; t += 256) {
        int seg = t >> 3, sub = t & 7;
        int ky = seg / 34, px = seg % 34;
        int y = i + ky - 1, xx = j0 + px - 1;
        uint4 v = {0u,0u,0u,0u};
        if (y >= 0 && y < Hq && xx >= 0 && xx < Wq)
            v = *(const uint4*)(xtb + ((size_t)y*Wq + xx)*64 + sub*8);
        *(uint4*)(halo + (ky*34 + px)*HSTRIDE + sub*8) = v;
    }
    __syncthreads();

    // MFMA: wave tile gM (co rows) x gN (pixel half); 9 taps x 2 c-chunks
    int gM = grp & 1, gN = grp >> 1;
    int n = lane & 15, quad = lane >> 4;
    float4v acc = {0.f,0.f,0.f,0.f};
#pragma unroll
    for (int k = 0; k < 9; ++k) {
        int ky = k/3, kx = k - (k/3)*3;
        const ushort_t* bbase = halo + (ky*34 + gN*16 + n + kx)*HSTRIDE + quad*8;
#pragma unroll
        for (int ks2 = 0; ks2 < 2; ++ks2) {
            short8 a  = *(const short8*)(cwf2 + (size_t)(((k*2+gM)*2+ks2)*512 + lane*8));
            short8 bf = *(const short8*)(bbase + ks2*32);
            acc = __builtin_amdgcn_mfma_f32_16x16x32_bf16(a, bf, acc, 0, 0, 0);
        }
    }
    int p = gN*16 + n;
    float* op = om + (size_t)((b*Hq + i)*Wq + j0 + p)*27;
#pragma unroll
    for (int r = 0; r < 4; ++r) {
        int co = gM*16 + quad*4 + r;
        if (co < 18) op[co] = acc[r] + off_b[co];
        else if (co < 27) {
            float v = acc[r] + msk_b[co-18];
            op[co] = 1.f/(1.f + __expf(-v));
        }
    }
}

// ---------------------------------------------------------------------------
// K2: deformable sampling + MFMA matmul. Block = 16 pixels, 4 waves.
// ---------------------------------------------------------------------------
__global__ void __launch_bounds__(256, 6) k_deform(const ushort_t* __restrict__ xt,
                                                   const float* __restrict__ om,
                                                   const ushort_t* __restrict__ wtf,
                                                   float* __restrict__ out) {
    __shared__ __align__(16) ushort_t s_s[16*SROW];   // 18,688 B
    __shared__ __align__(16) unsigned int s_pk[144*8]; // addrs+weights, 4,608 B
    __shared__ float s_om[432];                        // 16 px x 27 ch
    int blk = blockIdx.x;                 // 6400 = 4*160*10
    int jt = blk % 10, i = (blk/10) % Hq, b = blk/(10*Hq);
    int j0 = jt*16;
    int tid = threadIdx.x, lane = tid & 63, grp = tid >> 6;

    // stage om slice (contiguous 432 floats), coalesced
    const float* omrow = om + (size_t)((b*Hq + i)*Wq + j0)*27;
    if (tid < 432) s_om[tid] = omrow[tid];
    if (tid + 256 < 432) s_om[tid+256] = omrow[tid+256];
    __syncthreads();

    // Phase A: per (p,tap) gather addresses + premasked corner weights
    if (tid < 144) {
        int p = tid & 15, k = tid >> 4;
        const float* op = s_om + p*27;
        float oy = op[2*k], ox = op[2*k+1], m = op[18+k];
        float py = oy + (float)(i - 1 + k/3);
        float px = ox + (float)(j0 + p - 1 + (k - (k/3)*3));
        float fy = floorf(py), fx = floorf(px);
        int y0 = (int)fy, x0 = (int)fx;
        float wy1 = py - fy, wx1 = px - fx;
        float wy0 = 1.f - wy1, wx0 = 1.f - wx1;
        bool vy0 = (y0 >= 0) & (y0 < Hq),   vy1 = (y0+1 >= 0) & (y0+1 < Hq);
        bool vx0 = (x0 >= 0) & (x0 < Wq),   vx1 = (x0+1 >= 0) & (x0+1 < Wq);
        int yc0 = min(max(y0,   0), Hq-1), yc1 = min(max(y0+1, 0), Hq-1);
        int xc0 = min(max(x0,   0), Wq-1), xc1 = min(max(x0+1, 0), Wq-1);
        unsigned int* pk = s_pk + tid*8;
        pk[0] = (unsigned int)((yc0*Wq + xc0)*64);
        pk[1] = (unsigned int)((yc0*Wq + xc1)*64);
        pk[2] = (unsigned int)((yc1*Wq + xc0)*64);
        pk[3] = (unsigned int)((yc1*Wq + xc1)*64);
        pk[4] = __builtin_bit_cast(unsigned int, (vy0 && vx0) ? wy0*wx0*m : 0.f);
        pk[5] = __builtin_bit_cast(unsigned int, (vy0 && vx1) ? wy0*wx1*m : 0.f);
        pk[6] = __builtin_bit_cast(unsigned int, (vy1 && vx0) ? wy1*wx0*m : 0.f);
        pk[7] = __builtin_bit_cast(unsigned int, (vy1 && vx1) ? wy1*wx1*m : 0.f);
    }
    __syncthreads();

    // Phase B: wave-uniform (p,tap); bases readfirstlane'd -> saddr loads
    const ushort_t* xtb = xt + (size_t)b*HWq*64;
    for (int iter = 0; iter < 36; ++iter) {
        int t2 = iter*4 + grp;
        const unsigned int* pk = s_pk + t2*8;
        int a00 = __builtin_amdgcn_readfirstlane((int)pk[0]);
        int a01 = __builtin_amdgcn_readfirstlane((int)pk[1]);
        int a10 = __builtin_amdgcn_readfirstlane((int)pk[2]);
        int a11 = __builtin_amdgcn_readfirstlane((int)pk[3]);
        float w00 = __builtin_bit_cast(float, __builtin_amdgcn_readfirstlane((int)pk[4]));
        float w01 = __builtin_bit_cast(float, __builtin_amdgcn_readfirstlane((int)pk[5]));
        float w10 = __builtin_bit_cast(float, __builtin_amdgcn_readfirstlane((int)pk[6]));
        float w11 = __builtin_bit_cast(float, __builtin_amdgcn_readfirstlane((int)pk[7]));
        float v00 = bf2f(xtb[a00 + lane]);
        float v01 = bf2f(xtb[a01 + lane]);
        float v10 = bf2f(xtb[a10 + lane]);
        float v11 = bf2f(xtb[a11 + lane]);
        float sv = w00*v00 + w01*v01 + w10*v10 + w11*v11;
        int p = t2 & 15, k = t2 >> 4;
        s_s[p*SROW + lane*9 + k] = f2bf(sv);
    }
    __syncthreads();

    // Phase C: wave grp -> o rows [grp*16, +16), 16 pixels
    int n = lane & 15, quad = lane >> 4;
    float4v acc = {0.f,0.f,0.f,0.f};
    const ushort_t* arow = wtf + ((size_t)(grp*KS)*64 + lane)*8;
    const ushort_t* brow = s_s + n*SROW + quad*8;
#pragma unroll
    for (int ks = 0; ks < KS; ++ks) {
        short8 a  = *(const short8*)(arow + ks*512);
        short8 bf = *(const short8*)(brow + ks*32);
        acc = __builtin_amdgcn_mfma_f32_16x16x32_bf16(a, bf, acc, 0, 0, 0);
    }

    // Epilogue: row = o_local = quad*4+r, col = pixel = n (64B segments)
#pragma unroll
    for (int r = 0; r < 4; ++r) {
        int o = grp*16 + quad*4 + r;
        out[(((size_t)b*OUTq + o)*Hq + i)*Wq + j0 + n] = acc[r];
    }
}

// ---------------------------------------------------------------------------
extern "C" void kernel_launch(void* const* d_in, const int* in_sizes, int n_in,
                              void* d_out, int out_size, void* d_ws, size_t ws_size,
                              hipStream_t stream) {
    const float* x     = (const float*)d_in[0];
    const float* off_w = (const float*)d_in[1];
    const float* off_b = (const float*)d_in[2];
    const float* msk_w = (const float*)d_in[3];
    const float* msk_b = (const float*)d_in[4];
    const float* dcn_w = (const float*)d_in[5];
    float* out = (float*)d_out;

    char* ws = (char*)d_ws;
    ushort_t* xt   = (ushort_t*)ws;                                  // 13,107,200 B
    float*    om   = (float*)(ws + (size_t)Bq*HWq*64*2);             // 11,059,200 B
    ushort_t* wtf  = (ushort_t*)((char*)om + (size_t)Bq*HWq*27*4);   //     73,728 B
    ushort_t* cwf2 = wtf + 4*KS*512;                                 //     36,864 B

    hipLaunchKernelGGL(k_transpose_x, dim3(HWq/64, Bq), dim3(256), 0, stream, x, xt);
    hipLaunchKernelGGL(k_relayout, dim3((4*KS*512 + 9*2*2*512)/256), dim3(256),
                       0, stream, dcn_w, off_w, msk_w, wtf, cwf2);
    hipLaunchKernelGGL(k_offmask, dim3(Bq*Hq*5), dim3(256), 0, stream,
                       xt, cwf2, off_b, msk_b, om);
    hipLaunchKernelGGL(k_deform, dim3(Bq*Hq*10), dim3(256), 0, stream,
                       xt, om, wtf, out);
}

// Round 4
// 144.467 us; speedup vs baseline: 3.0030x; 1.1969x over previous
//
#include <hip/hip_runtime.h>
#include <hip/hip_bf16.h>
#include <math.h>

#define Bq 4
#define Cq 64
#define Hq 160
#define Wq 160
#define HWq (Hq*Wq)      // 25600
#define K2q 9
#define OUTq 64
#define KKq 576          // Cq*K2q
#define KS  18           // KKq/32
#define SROW 584         // padded kk row (bf16 units); 1168 B

typedef __attribute__((ext_vector_type(8))) short short8;
typedef __attribute__((ext_vector_type(4))) float float4v;
typedef unsigned short ushort_t;

__device__ __forceinline__ float bf2f(unsigned short u) {
    unsigned int v = ((unsigned int)u) << 16;
    return __builtin_bit_cast(float, v);
}
__device__ __forceinline__ unsigned short f2bf(float f) {  // RNE
    unsigned int u = __builtin_bit_cast(unsigned int, f);
    unsigned int r = u + 0x7fffu + ((u >> 16) & 1u);
    return (unsigned short)(r >> 16);
}
__device__ __forceinline__ float bflo(unsigned int u) {
    return __builtin_bit_cast(float, u << 16);
}
__device__ __forceinline__ float bfhi(unsigned int u) {
    return __builtin_bit_cast(float, u & 0xffff0000u);
}

// ---------------------------------------------------------------------------
// K0a: x [B][C][H][W] f32 -> xt [B][H][W][C] bf16
// ---------------------------------------------------------------------------
__global__ void __launch_bounds__(256) k_transpose_x(const float* __restrict__ x,
                                                     ushort_t* __restrict__ xt) {
    __shared__ float tile[64][65];
    int b = blockIdx.y, hw0 = blockIdx.x * 64;
    int lane = threadIdx.x & 63, grp = threadIdx.x >> 6;
#pragma unroll
    for (int i = 0; i < 16; ++i) {
        int c = grp*16 + i;
        tile[c][lane] = x[(b*Cq + c)*HWq + hw0 + lane];
    }
    __syncthreads();
#pragma unroll
    for (int i = 0; i < 16; ++i) {
        int hw = grp*16 + i;
        xt[((size_t)b*HWq + hw0 + hw)*64 + lane] = f2bf(tile[lane][hw]);
    }
}

// ---------------------------------------------------------------------------
// K0b: weight prepack (k-major K ordering: kk = k*64 + c).
//  wtf[((g*18+ks)*64+lane)*8+j] = bf16(dcn_w[m][c*9+kt]),
//     kk = ks*32+(lane>>4)*8+j, c = kk&63, kt = kk>>6, m = g*16+(lane&15)
//  cwf2[((k*2+g)*2+ks2)*512 + lane*8 + j]: per-tap conv A-frag (already k-major)
// ---------------------------------------------------------------------------
__global__ void k_relayout(const float* __restrict__ dcn_w,
                           const float* __restrict__ off_w,
                           const float* __restrict__ msk_w,
                           ushort_t* __restrict__ wtf,
                           ushort_t* __restrict__ cwf2) {
    int id = blockIdx.x*256 + threadIdx.x;
    if (id < 4*KS*512) {
        int j = id & 7, lane = (id>>3) & 63, ks = (id>>9) % KS, g = id/(512*KS);
        int kk = ks*32 + (lane>>4)*8 + j;
        int c  = kk & 63, kt = kk >> 6;
        int m  = g*16 + (lane&15);
        wtf[id] = f2bf(dcn_w[m*KKq + c*9 + kt]);
    }
    int id2 = id - 4*KS*512;
    if (id2 >= 0 && id2 < 9*2*2*512) {
        int j = id2 & 7, lane = (id2>>3) & 63;
        int ks2 = (id2>>9) & 1, g = (id2>>10) & 1, k = id2 >> 11;
        int co = g*16 + (lane&15);
        int c  = ks2*32 + (lane>>4)*8 + j;
        float w = 0.f;
        if (co < 18)      w = off_w[co*KKq + c*9 + k];
        else if (co < 27) w = msk_w[(co-18)*KKq + c*9 + k];
        cwf2[id2] = f2bf(w);
    }
}

// ---------------------------------------------------------------------------
// K1: offset+mask conv via dense halo + per-tap MFMA; coalesced epilogue.
// ---------------------------------------------------------------------------
#define HSTRIDE 72
__global__ void __launch_bounds__(256, 8) k_offmask(const ushort_t* __restrict__ xt,
                                                    const ushort_t* __restrict__ cwf2,
                                                    const float* __restrict__ off_b,
                                                    const float* __restrict__ msk_b,
                                                    float* __restrict__ om) {
    __shared__ __align__(16) ushort_t halo[3*34*HSTRIDE];   // 14,688 B
    __shared__ float s_o[32*28];                            //  3,584 B
    int blk = blockIdx.x;                 // 3200 = 4*160*5
    int jt = blk % 5, i = (blk/5) % Hq, b = blk/(5*Hq);
    int j0 = jt*32;
    int tid = threadIdx.x, lane = tid & 63, grp = tid >> 6;

    const ushort_t* xtb = xt + (size_t)b*HWq*64;
    for (int t = tid; t < 816; t += 256) {
        int seg = t >> 3, sub = t & 7;
        int ky = seg / 34, px = seg % 34;
        int y = i + ky - 1, xx = j0 + px - 1;
        uint4 v = {0u,0u,0u,0u};
        if (y >= 0 && y < Hq && xx >= 0 && xx < Wq)
            v = *(const uint4*)(xtb + ((size_t)y*Wq + xx)*64 + sub*8);
        *(uint4*)(halo + (ky*34 + px)*HSTRIDE + sub*8) = v;
    }
    __syncthreads();

    int gM = grp & 1, gN = grp >> 1;
    int n = lane & 15, quad = lane >> 4;
    float4v acc = {0.f,0.f,0.f,0.f};
#pragma unroll
    for (int k = 0; k < 9; ++k) {
        int ky = k/3, kx = k - (k/3)*3;
        const ushort_t* bbase = halo + (ky*34 + gN*16 + n + kx)*HSTRIDE + quad*8;
#pragma unroll
        for (int ks2 = 0; ks2 < 2; ++ks2) {
            short8 a  = *(const short8*)(cwf2 + (size_t)(((k*2+gM)*2+ks2)*512 + lane*8));
            short8 bf = *(const short8*)(bbase + ks2*32);
            acc = __builtin_amdgcn_mfma_f32_16x16x32_bf16(a, bf, acc, 0, 0, 0);
        }
    }
    int p = gN*16 + n;
#pragma unroll
    for (int r = 0; r < 4; ++r) {
        int co = gM*16 + quad*4 + r;
        if (co < 27) {
            float v = acc[r];
            if (co < 18) v += off_b[co];
            else { v += msk_b[co-18]; v = 1.f/(1.f + __expf(-v)); }
            s_o[p*28 + co] = v;
        }
    }
    __syncthreads();
    float* omrow = om + (size_t)((b*Hq + i)*Wq + j0)*27;
    for (int t = tid; t < 864; t += 256) {
        int p2 = t / 27, co2 = t - p2*27;
        omrow[t] = s_o[p2*28 + co2];
    }
}

// ---------------------------------------------------------------------------
// K2: deformable sampling + MFMA matmul. Block = 16 pixels, 4 waves.
// Phase B: half-wave per (p,tap), 2 channels/lane, descriptor-driven.
// ---------------------------------------------------------------------------
__global__ void __launch_bounds__(256, 6) k_deform(const ushort_t* __restrict__ xt,
                                                   const float* __restrict__ om,
                                                   const ushort_t* __restrict__ wtf,
                                                   float* __restrict__ out) {
    __shared__ __align__(16) ushort_t s_s[16*SROW];          // 18,688 B
    __shared__ __align__(16) unsigned int s_pk[144*12];      //  6,912 B
    int blk = blockIdx.x;                 // 6400 = 4*160*10
    int jt = blk % 10, i = (blk/10) % Hq, b = blk/(10*Hq);
    int j0 = jt*16;
    int tid = threadIdx.x, lane = tid & 63, grp = tid >> 6;

    // Phase A: per (p,tap) descriptors: corner byte-offsets, premasked
    // corner weights, LDS destination byte-offset.
    if (tid < 144) {
        int p = tid & 15, k = tid >> 4;
        const float* op = om + (size_t)((b*Hq + i)*Wq + j0 + p)*27;
        float oy = op[2*k], ox = op[2*k+1], m = op[18+k];
        float py = oy + (float)(i - 1 + k/3);
        float px = ox + (float)(j0 + p - 1 + (k - (k/3)*3));
        float fy = floorf(py), fx = floorf(px);
        int y0 = (int)fy, x0 = (int)fx;
        float wy1 = py - fy, wx1 = px - fx;
        float wy0 = 1.f - wy1, wx0 = 1.f - wx1;
        bool vy0 = (y0 >= 0) & (y0 < Hq),   vy1 = (y0+1 >= 0) & (y0+1 < Hq);
        bool vx0 = (x0 >= 0) & (x0 < Wq),   vx1 = (x0+1 >= 0) & (x0+1 < Wq);
        int yc0 = min(max(y0,   0), Hq-1), yc1 = min(max(y0+1, 0), Hq-1);
        int xc0 = min(max(x0,   0), Wq-1), xc1 = min(max(x0+1, 0), Wq-1);
        unsigned int* pk = s_pk + tid*12;
        pk[0] = (unsigned int)((yc0*Wq + xc0)*128);   // bytes into xtb
        pk[1] = (unsigned int)((yc0*Wq + xc1)*128);
        pk[2] = (unsigned int)((yc1*Wq + xc0)*128);
        pk[3] = (unsigned int)((yc1*Wq + xc1)*128);
        pk[4] = __builtin_bit_cast(unsigned int, (vy0 && vx0) ? wy0*wx0*m : 0.f);
        pk[5] = __builtin_bit_cast(unsigned int, (vy0 && vx1) ? wy0*wx1*m : 0.f);
        pk[6] = __builtin_bit_cast(unsigned int, (vy1 && vx0) ? wy1*wx0*m : 0.f);
        pk[7] = __builtin_bit_cast(unsigned int, (vy1 && vx1) ? wy1*wx1*m : 0.f);
        pk[8] = (unsigned int)(p*(SROW*2) + k*128);   // bytes into s_s
    }
    __syncthreads();

    // Phase B: half-wave handles one (p,tap); lane covers channels 2c,2c+1
    int lane4 = (lane & 31) * 4;
    int halfi = lane >> 5;
    const char* xtb = (const char*)(xt + (size_t)b*HWq*64);
    char* s_sb = (char*)s_s;
#pragma unroll 2
    for (int iter = 0; iter < 18; ++iter) {
        int t2h = iter*8 + grp*2 + halfi;
        const uint4* pkp = (const uint4*)(s_pk + t2h*12);
        uint4 A  = pkp[0];
        uint4 Wt = pkp[1];
        unsigned int dst = s_pk[t2h*12 + 8];
        unsigned int u00 = *(const unsigned int*)(xtb + A.x + lane4);
        unsigned int u01 = *(const unsigned int*)(xtb + A.y + lane4);
        unsigned int u10 = *(const unsigned int*)(xtb + A.z + lane4);
        unsigned int u11 = *(const unsigned int*)(xtb + A.w + lane4);
        float w00 = __builtin_bit_cast(float, Wt.x);
        float w01 = __builtin_bit_cast(float, Wt.y);
        float w10 = __builtin_bit_cast(float, Wt.z);
        float w11 = __builtin_bit_cast(float, Wt.w);
        float sl = w00*bflo(u00) + w01*bflo(u01) + w10*bflo(u10) + w11*bflo(u11);
        float sh = w00*bfhi(u00) + w01*bfhi(u01) + w10*bfhi(u10) + w11*bfhi(u11);
        __hip_bfloat162 h2 = __float22bfloat162_rn(make_float2(sl, sh));
        *(__hip_bfloat162*)(s_sb + dst + lane4) = h2;
    }
    __syncthreads();

    // Phase C: wave grp -> o rows [grp*16, +16), 16 pixels
    int n = lane & 15, quad = lane >> 4;
    float4v acc = {0.f,0.f,0.f,0.f};
    const ushort_t* arow = wtf + ((size_t)(grp*KS)*64 + lane)*8;
    const ushort_t* brow = s_s + n*SROW + quad*8;
#pragma unroll
    for (int ks = 0; ks < KS; ++ks) {
        short8 a  = *(const short8*)(arow + ks*512);
        short8 bf = *(const short8*)(brow + ks*32);
        acc = __builtin_amdgcn_mfma_f32_16x16x32_bf16(a, bf, acc, 0, 0, 0);
    }

    // Epilogue
#pragma unroll
    for (int r = 0; r < 4; ++r) {
        int o = grp*16 + quad*4 + r;
        out[(((size_t)b*OUTq + o)*Hq + i)*Wq + j0 + n] = acc[r];
    }
}

// ---------------------------------------------------------------------------
extern "C" void kernel_launch(void* const* d_in, const int* in_sizes, int n_in,
                              void* d_out, int out_size, void* d_ws, size_t ws_size,
                              hipStream_t stream) {
    const float* x     = (const float*)d_in[0];
    const float* off_w = (const float*)d_in[1];
    const float* off_b = (const float*)d_in[2];
    const float* msk_w = (const float*)d_in[3];
    const float* msk_b = (const float*)d_in[4];
    const float* dcn_w = (const float*)d_in[5];
    float* out = (float*)d_out;

    char* ws = (char*)d_ws;
    ushort_t* xt   = (ushort_t*)ws;                                  // 13,107,200 B
    float*    om   = (float*)(ws + (size_t)Bq*HWq*64*2);             // 11,059,200 B
    ushort_t* wtf  = (ushort_t*)((char*)om + (size_t)Bq*HWq*27*4);   //     73,728 B
    ushort_t* cwf2 = wtf + 4*KS*512;                                 //     36,864 B

    hipLaunchKernelGGL(k_transpose_x, dim3(HWq/64, Bq), dim3(256), 0, stream, x, xt);
    hipLaunchKernelGGL(k_relayout, dim3((4*KS*512 + 9*2*2*512)/256), dim3(256),
                       0, stream, dcn_w, off_w, msk_w, wtf, cwf2);
    hipLaunchKernelGGL(k_offmask, dim3(Bq*Hq*5), dim3(256), 0, stream,
                       xt, cwf2, off_b, msk_b, om);
    hipLaunchKernelGGL(k_deform, dim3(Bq*Hq*10), dim3(256), 0, stream,
                       xt, om, wtf, out);
}

// Round 5
// 134.456 us; speedup vs baseline: 3.2266x; 1.0745x over previous
//
#include <hip/hip_runtime.h>
#include <hip/hip_bf16.h>
#include <math.h>

#define Bq 4
#define Cq 64
#define Hq 160
#define Wq 160
#define HWq (Hq*Wq)      // 25600
#define K2q 9
#define OUTq 64
#define KKq 576          // Cq*K2q
#define KS  18           // KKq/32
#define SROW 584         // padded kk row (bf16 units); 1168 B
#define HSTRIDE 72       // halo px stride (ushorts) = 144 B

typedef __attribute__((ext_vector_type(8))) short short8;
typedef __attribute__((ext_vector_type(4))) float float4v;
typedef unsigned short ushort_t;

__device__ __forceinline__ unsigned short f2bf(float f) {  // RNE
    unsigned int u = __builtin_bit_cast(unsigned int, f);
    unsigned int r = u + 0x7fffu + ((u >> 16) & 1u);
    return (unsigned short)(r >> 16);
}
__device__ __forceinline__ float bflo(unsigned int u) {
    return __builtin_bit_cast(float, u << 16);
}
__device__ __forceinline__ float bfhi(unsigned int u) {
    return __builtin_bit_cast(float, u & 0xffff0000u);
}

// ---------------------------------------------------------------------------
// K_prep: x NCHW f32 -> xt NHWC bf16 (uint-vectorized stores), plus weight
// prepack piggybacked on the first 216 blocks of the y==0 slice.
//  wtf: A-frags of dcn_w, k-major kk = k*64+c.
//  cwf2: per-tap conv A-frags (27 rows offset+mask).
// ---------------------------------------------------------------------------
__global__ void __launch_bounds__(256) k_prep(const float* __restrict__ x,
                                              const float* __restrict__ dcn_w,
                                              const float* __restrict__ off_w,
                                              const float* __restrict__ msk_w,
                                              ushort_t* __restrict__ xt,
                                              ushort_t* __restrict__ wtf,
                                              ushort_t* __restrict__ cwf2) {
    __shared__ float tile[64][65];
    int b = blockIdx.y, hw0 = blockIdx.x * 64;
    int tid = threadIdx.x;
    int lane = tid & 63, grp = tid >> 6;
#pragma unroll
    for (int i = 0; i < 16; ++i) {
        int c = grp*16 + i;
        tile[c][lane] = x[(b*Cq + c)*HWq + hw0 + lane];
    }
    __syncthreads();
    int cp = tid & 31, hwg = tid >> 5;
#pragma unroll
    for (int it = 0; it < 8; ++it) {
        int hw = it*8 + hwg;
        unsigned int v = (unsigned int)f2bf(tile[2*cp][hw])
                       | ((unsigned int)f2bf(tile[2*cp+1][hw]) << 16);
        *(unsigned int*)(xt + ((size_t)b*HWq + hw0 + hw)*64 + 2*cp) = v;
    }
    if (blockIdx.y == 0 && blockIdx.x < 216) {
        int id = blockIdx.x*256 + tid;
        if (id < 4*KS*512) {
            int j = id & 7, ln = (id>>3) & 63, ks = (id>>9) % KS, g = id/(512*KS);
            int kk = ks*32 + (ln>>4)*8 + j;
            int c  = kk & 63, kt = kk >> 6;
            int m  = g*16 + (ln&15);
            wtf[id] = f2bf(dcn_w[m*KKq + c*9 + kt]);
        }
        int id2 = id - 4*KS*512;
        if (id2 >= 0 && id2 < 9*2*2*512) {
            int j = id2 & 7, ln = (id2>>3) & 63;
            int ks2 = (id2>>9) & 1, g = (id2>>10) & 1, k = id2 >> 11;
            int co = g*16 + (ln&15);
            int c  = ks2*32 + (ln>>4)*8 + j;
            float w = 0.f;
            if (co < 18)      w = off_w[co*KKq + c*9 + k];
            else if (co < 27) w = msk_w[(co-18)*KKq + c*9 + k];
            cwf2[id2] = f2bf(w);
        }
    }
}

// ---------------------------------------------------------------------------
// K_fused: per 16-px block: halo stage -> offset/mask conv (K-split MFMA) ->
// tap descriptors -> bilinear sampling -> main MFMA matmul -> store.
// LDS: union{halo(7776B)+conv partials(4096B) | s_s(18688B)} + s_pk(6912B)
// ---------------------------------------------------------------------------
__global__ void __launch_bounds__(256, 6) k_fused(const ushort_t* __restrict__ xt,
                                                  const ushort_t* __restrict__ cwf2,
                                                  const float* __restrict__ off_b,
                                                  const float* __restrict__ msk_b,
                                                  const ushort_t* __restrict__ wtf,
                                                  float* __restrict__ out) {
    __shared__ __align__(16) char s_mem[16*SROW*2];          // 18,688 B
    __shared__ __align__(16) unsigned int s_pk[144*12];      //  6,912 B
    ushort_t* halo   = (ushort_t*)s_mem;                     // [0, 7776)
    float*    s_part = (float*)(s_mem + 7776);               // [7776, 11872)
    ushort_t* s_s    = (ushort_t*)s_mem;                     // Phase B/C

    int blk = blockIdx.x;                 // 6400 = 4*160*10
    int jt = blk % 10, i = (blk/10) % Hq, b = blk/(10*Hq);
    int j0 = jt*16;
    int tid = threadIdx.x, lane = tid & 63, grp = tid >> 6;
    int n = lane & 15, quad = lane >> 4;

    // ---- Stage halo: 3 rows x 18 px x 64 ch bf16 (54 x 128B segments) ----
    const ushort_t* xtb = xt + (size_t)b*HWq*64;
    for (int t = tid; t < 432; t += 256) {
        int seg = t >> 3, sub = t & 7;
        int ky = seg / 18, px = seg % 18;
        int y = i + ky - 1, xx = j0 + px - 1;
        uint4 v = {0u,0u,0u,0u};
        if (y >= 0 && y < Hq && xx >= 0 && xx < Wq)
            v = *(const uint4*)(xtb + ((size_t)y*Wq + xx)*64 + sub*8);
        *(uint4*)(halo + (ky*18 + px)*HSTRIDE + sub*8) = v;
    }
    __syncthreads();

    // ---- Offset/mask conv: wave (gM, kh) over 9 K-steps each ----
    {
        int gM = grp & 1, kh = grp >> 1;
        float4v cacc = {0.f,0.f,0.f,0.f};
#pragma unroll
        for (int s = 0; s < 9; ++s) {
            int st = kh*9 + s;            // 0..17
            int k = st >> 1, ks2 = st & 1;
            int ky = k/3, kx = k - (k/3)*3;
            short8 a  = *(const short8*)(cwf2 + (size_t)(((k*2+gM)*2+ks2)*512 + lane*8));
            short8 bf = *(const short8*)(halo + (ky*18 + n + kx)*HSTRIDE + quad*8 + ks2*32);
            cacc = __builtin_amdgcn_mfma_f32_16x16x32_bf16(a, bf, cacc, 0, 0, 0);
        }
        *(float4v*)(s_part + grp*256 + lane*4) = cacc;
    }
    __syncthreads();

    // ---- Phase A: tap descriptors from conv partials ----
    if (tid < 144) {
        int p = tid & 15, k = tid >> 4;
        // rd(co): partial0 + partial1 at C-layout position (co, p)
        #define RD(co) (s_part[(((co)>>4)*256)       + ((((co)&15)>>2)*16 + p)*4 + ((co)&3)] + \
                        s_part[(2 + ((co)>>4))*256   + ((((co)&15)>>2)*16 + p)*4 + ((co)&3)])
        float oy = RD(2*k)   + off_b[2*k];
        float ox = RD(2*k+1) + off_b[2*k+1];
        float mv = RD(18+k)  + msk_b[k];
        #undef RD
        float m = 1.f/(1.f + __expf(-mv));
        float py = oy + (float)(i - 1 + k/3);
        float px = ox + (float)(j0 + p - 1 + (k - (k/3)*3));
        float fy = floorf(py), fx = floorf(px);
        int y0 = (int)fy, x0 = (int)fx;
        float wy1 = py - fy, wx1 = px - fx;
        float wy0 = 1.f - wy1, wx0 = 1.f - wx1;
        bool vy0 = (y0 >= 0) & (y0 < Hq),   vy1 = (y0+1 >= 0) & (y0+1 < Hq);
        bool vx0 = (x0 >= 0) & (x0 < Wq),   vx1 = (x0+1 >= 0) & (x0+1 < Wq);
        int yc0 = min(max(y0,   0), Hq-1), yc1 = min(max(y0+1, 0), Hq-1);
        int xc0 = min(max(x0,   0), Wq-1), xc1 = min(max(x0+1, 0), Wq-1);
        unsigned int* pk = s_pk + tid*12;
        pk[0] = (unsigned int)((yc0*Wq + xc0)*128);
        pk[1] = (unsigned int)((yc0*Wq + xc1)*128);
        pk[2] = (unsigned int)((yc1*Wq + xc0)*128);
        pk[3] = (unsigned int)((yc1*Wq + xc1)*128);
        pk[4] = __builtin_bit_cast(unsigned int, (vy0 && vx0) ? wy0*wx0*m : 0.f);
        pk[5] = __builtin_bit_cast(unsigned int, (vy0 && vx1) ? wy0*wx1*m : 0.f);
        pk[6] = __builtin_bit_cast(unsigned int, (vy1 && vx0) ? wy1*wx0*m : 0.f);
        pk[7] = __builtin_bit_cast(unsigned int, (vy1 && vx1) ? wy1*wx1*m : 0.f);
        pk[8] = (unsigned int)(p*(SROW*2) + k*128);
    }
    __syncthreads();

    // ---- Phase B: half-wave per (p,tap), 2 channels/lane ----
    int lane4 = (lane & 31) * 4;
    int halfi = lane >> 5;
    const char* xtbB = (const char*)xtb;
    char* s_sb = (char*)s_s;
#pragma unroll 2
    for (int iter = 0; iter < 18; ++iter) {
        int t2h = iter*8 + grp*2 + halfi;
        const uint4* pkp = (const uint4*)(s_pk + t2h*12);
        uint4 A  = pkp[0];
        uint4 Wt = pkp[1];
        unsigned int dst = s_pk[t2h*12 + 8];
        unsigned int u00 = *(const unsigned int*)(xtbB + A.x + lane4);
        unsigned int u01 = *(const unsigned int*)(xtbB + A.y + lane4);
        unsigned int u10 = *(const unsigned int*)(xtbB + A.z + lane4);
        unsigned int u11 = *(const unsigned int*)(xtbB + A.w + lane4);
        float w00 = __builtin_bit_cast(float, Wt.x);
        float w01 = __builtin_bit_cast(float, Wt.y);
        float w10 = __builtin_bit_cast(float, Wt.z);
        float w11 = __builtin_bit_cast(float, Wt.w);
        float sl = w00*bflo(u00) + w01*bflo(u01) + w10*bflo(u10) + w11*bflo(u11);
        float sh = w00*bfhi(u00) + w01*bfhi(u01) + w10*bfhi(u10) + w11*bfhi(u11);
        __hip_bfloat162 h2 = __float22bfloat162_rn(make_float2(sl, sh));
        *(__hip_bfloat162*)(s_sb + dst + lane4) = h2;
    }
    __syncthreads();

    // ---- Phase C: wave grp -> o rows [grp*16, +16), 16 pixels ----
    float4v acc = {0.f,0.f,0.f,0.f};
    const ushort_t* arow = wtf + ((size_t)(grp*KS)*64 + lane)*8;
    const ushort_t* brow = s_s + n*SROW + quad*8;
#pragma unroll
    for (int ks = 0; ks < KS; ++ks) {
        short8 a  = *(const short8*)(arow + ks*512);
        short8 bf = *(const short8*)(brow + ks*32);
        acc = __builtin_amdgcn_mfma_f32_16x16x32_bf16(a, bf, acc, 0, 0, 0);
    }

#pragma unroll
    for (int r = 0; r < 4; ++r) {
        int o = grp*16 + quad*4 + r;
        out[(((size_t)b*OUTq + o)*Hq + i)*Wq + j0 + n] = acc[r];
    }
}

// ---------------------------------------------------------------------------
extern "C" void kernel_launch(void* const* d_in, const int* in_sizes, int n_in,
                              void* d_out, int out_size, void* d_ws, size_t ws_size,
                              hipStream_t stream) {
    const float* x     = (const float*)d_in[0];
    const float* off_w = (const float*)d_in[1];
    const float* off_b = (const float*)d_in[2];
    const float* msk_w = (const float*)d_in[3];
    const float* msk_b = (const float*)d_in[4];
    const float* dcn_w = (const float*)d_in[5];
    float* out = (float*)d_out;

    char* ws = (char*)d_ws;
    ushort_t* xt   = (ushort_t*)ws;                  // 13,107,200 B
    ushort_t* wtf  = xt + (size_t)Bq*HWq*64;         //     73,728 B
    ushort_t* cwf2 = wtf + 4*KS*512;                 //     36,864 B

    hipLaunchKernelGGL(k_prep, dim3(HWq/64, Bq), dim3(256), 0, stream,
                       x, dcn_w, off_w, msk_w, xt, wtf, cwf2);
    hipLaunchKernelGGL(k_fused, dim3(Bq*Hq*10), dim3(256), 0, stream,
                       xt, cwf2, off_b, msk_b, wtf, out);
}